// Round 1
// baseline (115.011 us; speedup 1.0000x reference)
//
#include <hip/hip_runtime.h>

typedef float v2f __attribute__((ext_vector_type(2)));

// ---------------------------------------------------------------------------
// Layout (4 px/wave): group g = lane>>5 holds a packed pixel pair in v2f
// (.x = pixel 2g, .y = pixel 2g+1). q = lane&31. Amp index i = 8 bits
// w0..w7 (MSB..LSB): w0<->lane mask16, w1<->mask8, w2<->mask2, w3<->mask1,
// w4<->mask4; w5,w6,w7 <-> reg bits 2,1,0 of r in Sr[8]/Si[8].
// Grid 1024 blocks -> 4 blocks/CU -> 16 waves/CU (was 512 -> 2/CU).
// All hot FMA/MUL/ADD forced to v_pk_*_f32 (packed fp32) via inline asm.
// ---------------------------------------------------------------------------
template<int C>
__device__ __forceinline__ float dppmov(float x) {
  return __int_as_float(__builtin_amdgcn_update_dpp(0, __float_as_int(x), C, 0xF, 0xF, true));
}
template<int IMM>
__device__ __forceinline__ float dswz(float x) {
  return __int_as_float(__builtin_amdgcn_ds_swizzle(__float_as_int(x), IMM));
}
__device__ __forceinline__ float bperm(float x, int a) {
  return __int_as_float(__builtin_amdgcn_ds_bpermute(a, __float_as_int(x)));
}
template<int M>
__device__ __forceinline__ float bfly(float x) {
  if constexpr (M == 1)      return dppmov<0xB1>(x);   // quad_perm [1,0,3,2]
  else if constexpr (M == 2) return dppmov<0x4E>(x);   // quad_perm [2,3,0,1]
  else if constexpr (M == 3) return dppmov<0x1B>(x);   // quad_perm [3,2,1,0]
  else if constexpr (M == 8) return dppmov<0x128>(x);  // row_ror:8 == xor8
  else if constexpr (M == 4) return dswz<0x101F>(x);   // bit-mode xor4
  else                       return dswz<0x401F>(x);   // M==16: bit-mode xor16
}
template<int M>
__device__ __forceinline__ v2f bfly2(v2f v) {
  v2f o; o.x = bfly<M>(v.x); o.y = bfly<M>(v.y); return o;
}
__device__ __forceinline__ v2f sp(float s) { v2f v; v.x = s; v.y = s; return v; }

// Packed fp32 math, guaranteed (compiler was scalarizing v2f fma).
__device__ __forceinline__ v2f vfma(v2f a, v2f b, v2f c) {
  v2f d;
  asm("v_pk_fma_f32 %0, %1, %2, %3" : "=v"(d) : "v"(a), "v"(b), "v"(c));
  return d;
}
__device__ __forceinline__ v2f vmul2(v2f a, v2f b) {
  v2f d;
  asm("v_pk_mul_f32 %0, %1, %2" : "=v"(d) : "v"(a), "v"(b));
  return d;
}
__device__ __forceinline__ v2f vadd2(v2f a, v2f b) {
  v2f d;
  asm("v_pk_add_f32 %0, %1, %2" : "=v"(d) : "v"(a), "v"(b));
  return d;
}
__device__ __forceinline__ v2f vsub2(v2f a, v2f b) {
  v2f r; r.x = a.x - b.x; r.y = a.y - b.y; return r;
}

// ---------------------------------------------------------------------------
// Gate stages (8 state regs). crossG: 2x2 on lane-wire mask M, per-lane
// matrix selected by ctrl lane-bit CM; g[0..7]=plain U, g[8..15]=C*U.
// ---------------------------------------------------------------------------
template<int M, int CM>
__device__ __forceinline__ void crossG(v2f Sr[8], v2f Si[8],
    const float* g, int lane) {
  const bool hi = (lane & M) != 0;
  const bool ct = (lane & CM) != 0;
  float f0r = hi ? g[6]  : g[0],  f0i = hi ? g[7]  : g[1];
  float g0r = hi ? g[4]  : g[2],  g0i = hi ? g[5]  : g[3];
  float f1r = hi ? g[14] : g[8],  f1i = hi ? g[15] : g[9];
  float g1r = hi ? g[12] : g[10], g1i = hi ? g[13] : g[11];
  float fr = ct ? f1r : f0r, fi = ct ? f1i : f0i;
  float gr = ct ? g1r : g0r, gi = ct ? g1i : g0i;
  v2f vfr = sp(fr), vfi = sp(fi), vgr = sp(gr), vgi = sp(gi);
  v2f vfiN = sp(-fi), vgiN = sp(-gi);
#pragma unroll
  for (int r = 0; r < 8; ++r) {
    v2f pR = bfly2<M>(Sr[r]);
    v2f pI = bfly2<M>(Si[r]);
    v2f nR = vfma(vgiN, pI, vfma(vgr, pR, vfma(vfiN, Si[r], vmul2(vfr, Sr[r]))));
    v2f nI = vfma(vgi,  pR, vfma(vgr, pI, vfma(vfi,  Sr[r], vmul2(vfr, Si[r]))));
    Sr[r] = nR; Si[r] = nI;
  }
}

__device__ __forceinline__ void mixP(v2f& x0r, v2f& x0i, v2f& x1r, v2f& x1i,
    float m0r, float m0i, float m1r, float m1i,
    float m2r, float m2i, float m3r, float m3i) {
  v2f n0r = vfma(sp(-m1i), x1i, vfma(sp(m1r), x1r, vfma(sp(-m0i), x0i, vmul2(sp(m0r), x0r))));
  v2f n0i = vfma(sp( m1i), x1r, vfma(sp(m1r), x1i, vfma(sp( m0i), x0r, vmul2(sp(m0r), x0i))));
  v2f n1r = vfma(sp(-m3i), x1i, vfma(sp(m3r), x1r, vfma(sp(-m2i), x0i, vmul2(sp(m2r), x0r))));
  v2f n1i = vfma(sp( m3i), x1r, vfma(sp(m3r), x1i, vfma(sp( m2i), x0r, vmul2(sp(m2r), x0i))));
  x0r = n0r; x0i = n0i; x1r = n1r; x1i = n1i;
}

// F23: fused (F3*F2) 4x4 on wires 2,3 (lane masks 2,1) — unchanged masks,
// ctrl (wire1) moved from lane bit2 to bit3.
__device__ __forceinline__ void f23N(v2f Sr[8], v2f Si[8],
    const float* tab, int lane) {
  const int idx = ((lane >> 3) & 1) * 4 + (lane & 3);
  const float* rp = tab + idx * 8;
  const float c0r = rp[0], c0i = rp[1], c1r = rp[2], c1i = rp[3];
  const float c2r = rp[4], c2i = rp[5], c3r = rp[6], c3i = rp[7];
#pragma unroll
  for (int r = 0; r < 8; ++r) {
    v2f p1R = bfly2<1>(Sr[r]), p1I = bfly2<1>(Si[r]);
    v2f p2R = bfly2<2>(Sr[r]), p2I = bfly2<2>(Si[r]);
    v2f p3R = bfly2<3>(Sr[r]), p3I = bfly2<3>(Si[r]);
    v2f nR = vmul2(sp(c0r), Sr[r]);
    nR = vfma(sp(-c0i), Si[r], nR);
    nR = vfma(sp( c1r), p1R, nR);  nR = vfma(sp(-c1i), p1I, nR);
    nR = vfma(sp( c2r), p2R, nR);  nR = vfma(sp(-c2i), p2I, nR);
    nR = vfma(sp( c3r), p3R, nR);  nR = vfma(sp(-c3i), p3I, nR);
    v2f nI = vmul2(sp(c0i), Sr[r]);
    nI = vfma(sp(c0r), Si[r], nI);
    nI = vfma(sp(c1i), p1R, nI);   nI = vfma(sp(c1r), p1I, nI);
    nI = vfma(sp(c2i), p2R, nI);   nI = vfma(sp(c2r), p2I, nI);
    nI = vfma(sp(c3i), p3R, nI);   nI = vfma(sp(c3r), p3I, nI);
    Sr[r] = nR; Si[r] = nI;
  }
}

// F5: u3(w5)+cu3(4->5): ctrl lane mask4 (select), target r bit2.
__device__ __forceinline__ void f5N(v2f Sr[8], v2f Si[8], const float* g, int lane) {
  const bool ct = (lane & 4) != 0;
  float m[8];
#pragma unroll
  for (int jj = 0; jj < 8; ++jj) m[jj] = ct ? g[8 + jj] : g[jj];
#pragma unroll
  for (int r = 0; r < 4; ++r)
    mixP(Sr[r], Si[r], Sr[r + 4], Si[r + 4],
         m[0], m[1], m[2], m[3], m[4], m[5], m[6], m[7]);
}

// F67: fused (F7*F6) 4x4 per reg-quad (r bits 1,0); matrix by r bit2 (w5).
__device__ __forceinline__ void f67N(v2f Sr[8], v2f Si[8], const float* T) {
#pragma unroll
  for (int qd = 0; qd < 2; ++qd) {
    const int B = qd * 4;
    const float* M = T + qd * 32;
    v2f ar0 = Sr[B+0], ai0 = Si[B+0], ar1 = Sr[B+1], ai1 = Si[B+1];
    v2f ar2 = Sr[B+2], ai2 = Si[B+2], ar3 = Sr[B+3], ai3 = Si[B+3];
#pragma unroll
    for (int rp = 0; rp < 4; ++rp) {
      const float* Mr = M + rp * 8;
      v2f nR = vmul2(sp(Mr[0]), ar0);
      nR = vfma(sp(-Mr[1]), ai0, nR);
      nR = vfma(sp( Mr[2]), ar1, nR);
      nR = vfma(sp(-Mr[3]), ai1, nR);
      nR = vfma(sp( Mr[4]), ar2, nR);
      nR = vfma(sp(-Mr[5]), ai2, nR);
      nR = vfma(sp( Mr[6]), ar3, nR);
      nR = vfma(sp(-Mr[7]), ai3, nR);
      v2f nI = vmul2(sp(Mr[1]), ar0);
      nI = vfma(sp(Mr[0]), ai0, nI);
      nI = vfma(sp(Mr[3]), ar1, nI);
      nI = vfma(sp(Mr[2]), ai1, nI);
      nI = vfma(sp(Mr[5]), ar2, nI);
      nI = vfma(sp(Mr[4]), ai2, nI);
      nI = vfma(sp(Mr[7]), ar3, nI);
      nI = vfma(sp(Mr[6]), ai3, nI);
      Sr[B + rp] = nR; Si[B + rp] = nI;
    }
  }
}

// F8': fused cu3(7->0)+next u3(w0): ctrl r bit0, target lane mask 16.
__device__ __forceinline__ void f8pN(v2f Sr[8], v2f Si[8],
    const float* g, int lane) {
  const bool hi = (lane & 16) != 0;
  float fr[2], fi[2], gr[2], gi[2];
  fr[0] = hi ? g[6]  : g[0];  fi[0] = hi ? g[7]  : g[1];
  gr[0] = hi ? g[4]  : g[2];  gi[0] = hi ? g[5]  : g[3];
  fr[1] = hi ? g[14] : g[8];  fi[1] = hi ? g[15] : g[9];
  gr[1] = hi ? g[12] : g[10]; gi[1] = hi ? g[13] : g[11];
#pragma unroll
  for (int r = 0; r < 8; ++r) {
    const int m = r & 1;
    v2f pR = bfly2<16>(Sr[r]);
    v2f pI = bfly2<16>(Si[r]);
    v2f nR = vfma(sp(-gi[m]), pI, vfma(sp(gr[m]), pR, vfma(sp(-fi[m]), Si[r], vmul2(sp(fr[m]), Sr[r]))));
    v2f nI = vfma(sp( gi[m]), pR, vfma(sp(gr[m]), pI, vfma(sp( fi[m]), Sr[r], vmul2(sp(fr[m]), Si[r]))));
    Sr[r] = nR; Si[r] = nI;
  }
}
// F8 final standalone cu3(7->0): odd r only, target lane mask 16.
__device__ __forceinline__ void f8N(v2f Sr[8], v2f Si[8],
    const float* g, int lane) {
  const bool hi = (lane & 16) != 0;
  const float fr = hi ? g[6] : g[0], fi = hi ? g[7] : g[1];
  const float gr = hi ? g[4] : g[2], gi = hi ? g[5] : g[3];
  v2f vfr = sp(fr), vfi = sp(fi), vgr = sp(gr), vgi = sp(gi);
  v2f vfiN = sp(-fi), vgiN = sp(-gi);
#pragma unroll
  for (int r = 1; r < 8; r += 2) {
    v2f pR = bfly2<16>(Sr[r]);
    v2f pI = bfly2<16>(Si[r]);
    v2f nR = vfma(vgiN, pI, vfma(vgr, pR, vfma(vfiN, Si[r], vmul2(vfr, Sr[r]))));
    v2f nI = vfma(vgi,  pR, vfma(vgr, pI, vfma(vfi,  Sr[r], vmul2(vfr, Si[r]))));
    Sr[r] = nR; Si[r] = nI;
  }
}

// Off-diagonal pair sum for a lane-cross wire (mask M), dual accumulators
// to avoid v2f negation.
template<int M>
__device__ __forceinline__ void crossO(const v2f Sr[8], const v2f Si[8],
                                       v2f& re, v2f& im) {
  v2f r = sp(0.0f), iP = sp(0.0f), iN = sp(0.0f);
#pragma unroll
  for (int k = 0; k < 8; ++k) {
    v2f pr = bfly2<M>(Sr[k]);
    v2f pi = bfly2<M>(Si[k]);
    r  = vfma(Sr[k], pr, r);
    r  = vfma(Si[k], pi, r);
    iP = vfma(Si[k], pr, iP);
    iN = vfma(Sr[k], pi, iN);
  }
  re = r; im = vsub2(iP, iN);
}

// ---------------------------------------------------------------------------
// Prep helpers (unchanged math).
// ---------------------------------------------------------------------------
__device__ __forceinline__ void mm2(const float* A, const float* B, float* D) {
  D[0] = A[0]*B[0] - A[1]*B[1] + A[2]*B[4] - A[3]*B[5];
  D[1] = A[0]*B[1] + A[1]*B[0] + A[2]*B[5] + A[3]*B[4];
  D[2] = A[0]*B[2] - A[1]*B[3] + A[2]*B[6] - A[3]*B[7];
  D[3] = A[0]*B[3] + A[1]*B[2] + A[2]*B[7] + A[3]*B[6];
  D[4] = A[4]*B[0] - A[5]*B[1] + A[6]*B[4] - A[7]*B[5];
  D[5] = A[4]*B[1] + A[5]*B[0] + A[6]*B[5] + A[7]*B[4];
  D[6] = A[4]*B[2] - A[5]*B[3] + A[6]*B[6] - A[7]*B[7];
  D[7] = A[4]*B[3] + A[5]*B[2] + A[6]*B[7] + A[7]*B[6];
}
__device__ __forceinline__ void u3fill(const float* src, float* o) {
  float th = src[0], ph = src[1], lam = src[2];
  float c = cosf(0.5f * th), s = sinf(0.5f * th);
  float cl = cosf(lam), sl = sinf(lam);
  float cp = cosf(ph), spv = sinf(ph);
  float cpl = cosf(ph + lam), spl = sinf(ph + lam);
  o[0] = c;        o[1] = 0.0f;
  o[2] = -cl * s;  o[3] = -sl * s;
  o[4] = cp * s;   o[5] = spv * s;
  o[6] = cpl * c;  o[7] = spl * c;
}

// ---------------------------------------------------------------------------
// Fused kernel: conv + qsim + direct-Pauli measurement + FC. 4 px/wave.
// ---------------------------------------------------------------------------
__global__ __launch_bounds__(256, 4) void qconv_kernel(
    const float* __restrict__ x, const float* __restrict__ cw,
    const float* __restrict__ cb, const float* __restrict__ u3p,
    const float* __restrict__ cu3p, const float* __restrict__ fcw,
    const float* __restrict__ fcb, float* __restrict__ out) {
  __shared__ float Us[40][8];
  __shared__ float Cs[40][8];
  __shared__ float Gs[640];
  __shared__ float FCWs[768];   // transposed: [u=0..23][ch=0..31]
  __shared__ float F23t[320];
  __shared__ float F67t[320];

  // ---- in-block prep ----
  {
    const int t = threadIdx.x;
    if (t < 40) u3fill(u3p + t * 3, Us[t]);
    if (t >= 64 && t < 104) u3fill(cu3p + (t - 64) * 3, Cs[t - 64]);
    for (int i = t; i < 768; i += 256) {
      int u = i >> 5, ch = i & 31;
      // lane wires now 0..4 (crossO double-counts pairs); reg wires 5..7
      // need the x2 for the single-orientation pair sums (mx/my only).
      float sc = (u >= 8 && (u & 7) >= 5) ? 2.0f : 1.0f;
      FCWs[i] = fcw[ch * 24 + u] * sc;
    }
    __syncthreads();
    if (t == 0) {
#pragma unroll
      for (int j = 0; j < 8; ++j) Gs[j] = Us[0][j];
    } else if (t < 36) {
      int j = t - 1, b = j / 7, k = j % 7;
      float* dst = Gs + 8 + b * 112 + k * 16;
      const float* U = Us[b * 8 + k + 1];
      const float* C = Cs[b * 8 + k];
#pragma unroll
      for (int u = 0; u < 8; ++u) dst[u] = U[u];
      mm2(C, U, dst + 8);
    } else if (t < 40) {
      int b = t - 36;
      float* dst = Gs + 568 + b * 16;
      const float* U = Us[(b + 1) * 8];
      const float* C = Cs[b * 8 + 7];
#pragma unroll
      for (int u = 0; u < 8; ++u) dst[u] = U[u];
      mm2(U, C, dst + 8);
    } else if (t == 40) {
#pragma unroll
      for (int j = 0; j < 8; ++j) Gs[632 + j] = Cs[39][j];
    }
    __syncthreads();
    if (t < 40) {
      int b = t >> 3, idx = t & 7;
      int ct = idx >> 2, row = idx & 3;
      const float* M2 = Gs + 8 + b * 112 + 16 + ct * 8;
      int w2p = row >> 1, w3p = row & 1;
      const float* M3 = Gs + 8 + b * 112 + 32 + w2p * 8;
      float* dst = F23t + b * 64 + idx * 8;
#pragma unroll
      for (int k = 0; k < 4; ++k) {
        int w2 = w2p ^ (k >> 1), w3 = w3p ^ (k & 1);
        float a_r = M2[(w2p * 2 + w2) * 2], a_i = M2[(w2p * 2 + w2) * 2 + 1];
        float b_r = M3[(w3p * 2 + w3) * 2], b_i = M3[(w3p * 2 + w3) * 2 + 1];
        dst[k * 2]     = a_r * b_r - a_i * b_i;
        dst[k * 2 + 1] = a_r * b_i + a_i * b_r;
      }
    } else if (t >= 64 && t < 104) {
      int u = t - 64;
      int b = u >> 3, idx = u & 7;
      int ct = idx >> 2, rp = idx & 3;
      const float* M6 = Gs + 8 + b * 112 + 80 + ct * 8;
      int b1p = rp >> 1, b0p = rp & 1;
      const float* M7 = Gs + 8 + b * 112 + 96 + b1p * 8;
      float* dst = F67t + b * 64 + ct * 32 + rp * 8;
#pragma unroll
      for (int c = 0; c < 4; ++c) {
        int b1 = c >> 1, b0 = c & 1;
        float a_r = M6[(b1p * 2 + b1) * 2], a_i = M6[(b1p * 2 + b1) * 2 + 1];
        float b_r = M7[(b0p * 2 + b0) * 2], b_i = M7[(b0p * 2 + b0) * 2 + 1];
        dst[c * 2]     = a_r * b_r - a_i * b_i;
        dst[c * 2 + 1] = a_r * b_i + a_i * b_r;
      }
    }
    __syncthreads();
  }

  const int lane = threadIdx.x & 63;
  const int wid = __builtin_amdgcn_readfirstlane(
      (int)((blockIdx.x * blockDim.x + threadIdx.x) >> 6));
  const int p0 = wid * 4;
  const int q = lane & 31;

  // ---- conv: lane = (px = lane>>4, ichalf = (lane>>3)&1, oc = lane&7) ----
  float ang;
  {
    const int px = lane >> 4;
    const int oc = lane & 7;
    const int ichalf = (lane >> 3) & 1;
    const int p  = p0 + px;
    const int b  = p >> 12;
    const int hh = (p >> 6) & 63;
    const int wim = p & 63;
    float acc = ichalf ? 0.0f : cb[oc];
    const int ic0 = ichalf * 8;
#pragma unroll 4
    for (int ici = 0; ici < 8; ++ici) {
      const int ic = ic0 + ici;
      const float* wp = cw + (oc * 16 + ic) * 9;
      const float* xp = x + (b * 16 + ic) * 4096;
#pragma unroll
      for (int kh = 0; kh < 3; ++kh) {
        int ih = hh + kh - 1;
        bool rok = (unsigned)ih < 64u;
        int ihc = rok ? ih : 0;
#pragma unroll
        for (int kw = 0; kw < 3; ++kw) {
          int iw = wim + kw - 1;
          bool ok = rok && ((unsigned)iw < 64u);
          int iwc = ((unsigned)iw < 64u) ? iw : 0;
          float xv = xp[ihc * 64 + iwc];
          acc = fmaf(ok ? xv : 0.0f, wp[kh * 3 + kw], acc);
        }
      }
    }
    ang = acc + bfly<8>(acc);   // combine the two ic-halves
  }

  // ---- gather 16 angles, build product state with F0 folded ----
  v2f Sr[8], Si[8];
  {
    const int gb = lane & 32;
    float aA[8], aB[8];
#pragma unroll
    for (int w = 0; w < 8; ++w) {
      aA[w] = bperm(ang, (gb + w) << 2);
      aB[w] = bperm(ang, (gb + 16 + w) << 2);
    }
    float cA[8], sA[8], cB[8], sB[8];
#pragma unroll
    for (int w = 0; w < 8; ++w) {
      __sincosf(0.5f * aA[w], &sA[w], &cA[w]);
      __sincosf(0.5f * aB[w], &sB[w], &cB[w]);
    }
    v2f c0; c0.x = cA[0]; c0.y = cB[0];
    v2f s0; s0.x = sA[0]; s0.y = sB[0];
    v2f c0r = vfma(sp(Gs[2]), s0, vmul2(sp(Gs[0]), c0));
    v2f c0i = vfma(sp(Gs[3]), s0, vmul2(sp(Gs[1]), c0));
    v2f s0r = vfma(sp(Gs[6]), s0, vmul2(sp(Gs[4]), c0));
    v2f s0i = vfma(sp(Gs[7]), s0, vmul2(sp(Gs[5]), c0));
    const bool w0 = (q & 16) != 0;
    v2f selR = w0 ? s0r : c0r;
    v2f selI = w0 ? s0i : c0i;
    // lane wires 1..4: masks 8,2,1,4
    float fA = ((q & 8) ? sA[1] : cA[1]) * ((q & 2) ? sA[2] : cA[2])
             * ((q & 1) ? sA[3] : cA[3]) * ((q & 4) ? sA[4] : cA[4]);
    float fB = ((q & 8) ? sB[1] : cB[1]) * ((q & 2) ? sB[2] : cB[2])
             * ((q & 1) ? sB[3] : cB[3]) * ((q & 4) ? sB[4] : cB[4]);
    v2f f; f.x = fA; f.y = fB;
    selR = vmul2(selR, f);
    selI = vmul2(selI, f);
    v2f uu[4];
    uu[0].x = cA[6]*cA[7]; uu[1].x = cA[6]*sA[7];
    uu[2].x = sA[6]*cA[7]; uu[3].x = sA[6]*sA[7];
    uu[0].y = cB[6]*cB[7]; uu[1].y = cB[6]*sB[7];
    uu[2].y = sB[6]*cB[7]; uu[3].y = sB[6]*sB[7];
    v2f v5[2];
    v5[0].x = cA[5]; v5[0].y = cB[5];
    v5[1].x = sA[5]; v5[1].y = sB[5];
#pragma unroll
    for (int r = 0; r < 8; ++r) {
      v2f base = vmul2(v5[r >> 2], uu[r & 3]);
      Sr[r] = vmul2(selR, base);
      Si[r] = vmul2(selI, base);
    }
  }

  // ---- fused circuit: F0 in init; F1,F23,F4,F5,F67,F8' per block ----
  for (int b = 0; b < 5; ++b) {
    const float* base = Gs + 8 + b * 112;
    crossG<8, 16>(Sr, Si, base + 0, lane);      // F1: tgt w1(m8), ctrl w0(m16)
    f23N(Sr, Si, F23t + b * 64, lane);          // F23: m2,m1; ctrl m8
    crossG<4, 1>(Sr, Si, base + 48, lane);      // F4: tgt w4(m4), ctrl w3(m1)
    f5N(Sr, Si, base + 64, lane);               // F5: tgt r bit2, ctrl m4
    f67N(Sr, Si, F67t + b * 64);                // F67: reg 4x4
    if (b < 4) f8pN(Sr, Si, Gs + 568 + b * 16, lane); // F8': tgt m16, ctrl r0
  }
  f8N(Sr, Si, Gs + 632, lane);

  // ---- per-lane measurement partials ----
  float sg[5];
  sg[0] = (q & 16) ? -1.0f : 1.0f;
  sg[1] = (q & 8)  ? -1.0f : 1.0f;
  sg[2] = (q & 2)  ? -1.0f : 1.0f;
  sg[3] = (q & 1)  ? -1.0f : 1.0f;
  sg[4] = (q & 4)  ? -1.0f : 1.0f;

  v2f PT[24];
  {
    v2f re, im;
    crossO<16>(Sr, Si, re, im); PT[8]  = re; PT[16] = vmul2(sp(sg[0]), im);
    crossO<8>(Sr, Si, re, im);  PT[9]  = re; PT[17] = vmul2(sp(sg[1]), im);
    crossO<2>(Sr, Si, re, im);  PT[10] = re; PT[18] = vmul2(sp(sg[2]), im);
    crossO<1>(Sr, Si, re, im);  PT[11] = re; PT[19] = vmul2(sp(sg[3]), im);
    crossO<4>(Sr, Si, re, im);  PT[12] = re; PT[20] = vmul2(sp(sg[4]), im);

    // reg-wire off-diagonal pairs (single orientation; x2 folded into FCWs)
    v2f rA, iP, iN;
    rA = sp(0.0f); iP = sp(0.0f); iN = sp(0.0f);
#pragma unroll
    for (int r = 0; r < 4; ++r) {          // w5: (r, r+4)
      rA = vfma(Sr[r], Sr[r+4], rA); rA = vfma(Si[r], Si[r+4], rA);
      iP = vfma(Si[r], Sr[r+4], iP); iN = vfma(Sr[r], Si[r+4], iN);
    }
    PT[13] = rA; PT[21] = vsub2(iP, iN);
    rA = sp(0.0f); iP = sp(0.0f); iN = sp(0.0f);
#pragma unroll
    for (int t = 0; t < 4; ++t) {          // w6: (lo, lo+2), lo in {0,1,4,5}
      const int lo = (t & 1) + (t >> 1) * 4;
      rA = vfma(Sr[lo], Sr[lo+2], rA); rA = vfma(Si[lo], Si[lo+2], rA);
      iP = vfma(Si[lo], Sr[lo+2], iP); iN = vfma(Sr[lo], Si[lo+2], iN);
    }
    PT[14] = rA; PT[22] = vsub2(iP, iN);
    rA = sp(0.0f); iP = sp(0.0f); iN = sp(0.0f);
#pragma unroll
    for (int t = 0; t < 4; ++t) {          // w7: (2t, 2t+1)
      const int lo = 2 * t;
      rA = vfma(Sr[lo], Sr[lo+1], rA); rA = vfma(Si[lo], Si[lo+1], rA);
      iP = vfma(Si[lo], Sr[lo+1], iP); iN = vfma(Sr[lo], Si[lo+1], iN);
    }
    PT[15] = rA; PT[23] = vsub2(iP, iN);

    // Z: probabilities
    v2f P[8];
#pragma unroll
    for (int r = 0; r < 8; ++r) P[r] = vfma(Si[r], Si[r], vmul2(Sr[r], Sr[r]));
    v2f t01[4];
#pragma unroll
    for (int k = 0; k < 4; ++k) t01[k] = vadd2(P[2*k], P[2*k+1]);
    v2f q0 = vadd2(t01[0], t01[1]), q1 = vadd2(t01[2], t01[3]);
    v2f p  = vadd2(q0, q1);
    PT[5] = vsub2(q0, q1);                                    // w5 (r bit2)
    PT[6] = vadd2(vsub2(t01[0], t01[1]), vsub2(t01[2], t01[3])); // w6
    PT[7] = vadd2(vadd2(vsub2(P[0], P[1]), vsub2(P[2], P[3])),
                  vadd2(vsub2(P[4], P[5]), vsub2(P[6], P[7]))); // w7
    PT[0] = vmul2(sp(sg[0]), p);
    PT[1] = vmul2(sp(sg[1]), p);
    PT[2] = vmul2(sp(sg[2]), p);
    PT[3] = vmul2(sp(sg[3]), p);
    PT[4] = vmul2(sp(sg[4]), p);
  }

  // ---- group-reduce partials (32 lanes, both pixels), then per-channel FC
  const int j = q & 15;
  const bool isB = (q & 16) != 0;
  float mm[24];
#pragma unroll
  for (int t = 0; t < 24; ++t) {
    // own component + partner's (opposite) component via one xor16 swizzle
    float own = isB ? PT[t].y : PT[t].x;
    float oth = isB ? PT[t].x : PT[t].y;
    float s = own + bfly<16>(oth);
    s += bfly<1>(s);
    s += bfly<2>(s);
    s += bfly<4>(s);
    s += bfly<8>(s);                      // completes the 16-lane half sum
    mm[t] = s;
  }

  const int g = lane >> 5;
  const int p = p0 + 2 * g + (isB ? 1 : 0);
  const int ob = (p >> 12) * 131072 + (p & 4095);
#pragma unroll
  for (int k = 0; k < 2; ++k) {
    const int ch = 2 * j + k;
    float acc = fcb[ch];
#pragma unroll
    for (int u = 0; u < 24; ++u) acc = fmaf(mm[u], FCWs[u * 32 + ch], acc);
    out[ob + ch * 4096] = acc;
  }
}

extern "C" void kernel_launch(void* const* d_in, const int* in_sizes, int n_in,
                              void* d_out, int out_size, void* d_ws, size_t ws_size,
                              hipStream_t stream) {
  const float* x      = (const float*)d_in[0];
  const float* conv_w = (const float*)d_in[1];
  const float* conv_b = (const float*)d_in[2];
  const float* u3p    = (const float*)d_in[3];
  const float* cu3p   = (const float*)d_in[4];
  const float* fcw    = (const float*)d_in[5];
  const float* fcb    = (const float*)d_in[6];
  float* out = (float*)d_out;

  qconv_kernel<<<1024, 256, 0, stream>>>(x, conv_w, conv_b, u3p, cu3p,
                                         fcw, fcb, out);
}

// Round 2
// 110.159 us; speedup vs baseline: 1.0440x; 1.0440x over previous
//
#include <hip/hip_runtime.h>

typedef float v2f __attribute__((ext_vector_type(2)));

// ---------------------------------------------------------------------------
// Layout (4 px/wave): group g = lane>>5 holds a packed pixel pair in v2f
// (.x = pixel 2g, .y = pixel 2g+1). q = lane&31. Amp index i = 8 bits
// w0..w7 (MSB..LSB): w0<->lane mask16, w1<->mask8, w2<->mask2, w3<->mask1,
// w4<->mask4; w5,w6,w7 <-> reg bits 2,1,0 of r in Sr[8]/Si[8].
// Grid 1024 blocks -> 4 blocks/CU -> 16 waves/CU.
// Math uses plain v2f intrinsics: compiler scalarizes to v_fma_f32 with
// free neg/abs modifiers and SGPR operands (round-1's inline-asm v_pk_*
// added ~46% VALU from alignment copies + lost modifiers — reverted).
// ---------------------------------------------------------------------------
template<int C>
__device__ __forceinline__ float dppmov(float x) {
  return __int_as_float(__builtin_amdgcn_update_dpp(0, __float_as_int(x), C, 0xF, 0xF, true));
}
template<int IMM>
__device__ __forceinline__ float dswz(float x) {
  return __int_as_float(__builtin_amdgcn_ds_swizzle(__float_as_int(x), IMM));
}
__device__ __forceinline__ float bperm(float x, int a) {
  return __int_as_float(__builtin_amdgcn_ds_bpermute(a, __float_as_int(x)));
}
template<int M>
__device__ __forceinline__ float bfly(float x) {
  if constexpr (M == 1)      return dppmov<0xB1>(x);   // quad_perm [1,0,3,2]
  else if constexpr (M == 2) return dppmov<0x4E>(x);   // quad_perm [2,3,0,1]
  else if constexpr (M == 3) return dppmov<0x1B>(x);   // quad_perm [3,2,1,0]
  else if constexpr (M == 8) return dppmov<0x128>(x);  // row_ror:8 == xor8
  else if constexpr (M == 4) return dswz<0x101F>(x);   // bit-mode xor4
  else                       return dswz<0x401F>(x);   // M==16: bit-mode xor16
}
template<int M>
__device__ __forceinline__ v2f bfly2(v2f v) {
  v2f o; o.x = bfly<M>(v.x); o.y = bfly<M>(v.y); return o;
}
__device__ __forceinline__ v2f sp(float s) { v2f v; v.x = s; v.y = s; return v; }

__device__ __forceinline__ v2f vfma(v2f a, v2f b, v2f c) {
  return __builtin_elementwise_fma(a, b, c);
}
__device__ __forceinline__ v2f vmul2(v2f a, v2f b) { return a * b; }
__device__ __forceinline__ v2f vadd2(v2f a, v2f b) { return a + b; }
__device__ __forceinline__ v2f vsub2(v2f a, v2f b) { return a - b; }

// ---------------------------------------------------------------------------
// Gate stages (8 state regs). crossG: 2x2 on lane-wire mask M, per-lane
// matrix selected by ctrl lane-bit CM; g[0..7]=plain U, g[8..15]=C*U.
// ---------------------------------------------------------------------------
template<int M, int CM>
__device__ __forceinline__ void crossG(v2f Sr[8], v2f Si[8],
    const float* g, int lane) {
  const bool hi = (lane & M) != 0;
  const bool ct = (lane & CM) != 0;
  float f0r = hi ? g[6]  : g[0],  f0i = hi ? g[7]  : g[1];
  float g0r = hi ? g[4]  : g[2],  g0i = hi ? g[5]  : g[3];
  float f1r = hi ? g[14] : g[8],  f1i = hi ? g[15] : g[9];
  float g1r = hi ? g[12] : g[10], g1i = hi ? g[13] : g[11];
  float fr = ct ? f1r : f0r, fi = ct ? f1i : f0i;
  float gr = ct ? g1r : g0r, gi = ct ? g1i : g0i;
  v2f vfr = sp(fr), vfi = sp(fi), vgr = sp(gr), vgi = sp(gi);
  v2f vfiN = sp(-fi), vgiN = sp(-gi);
#pragma unroll
  for (int r = 0; r < 8; ++r) {
    v2f pR = bfly2<M>(Sr[r]);
    v2f pI = bfly2<M>(Si[r]);
    v2f nR = vfma(vgiN, pI, vfma(vgr, pR, vfma(vfiN, Si[r], vmul2(vfr, Sr[r]))));
    v2f nI = vfma(vgi,  pR, vfma(vgr, pI, vfma(vfi,  Sr[r], vmul2(vfr, Si[r]))));
    Sr[r] = nR; Si[r] = nI;
  }
}

__device__ __forceinline__ void mixP(v2f& x0r, v2f& x0i, v2f& x1r, v2f& x1i,
    float m0r, float m0i, float m1r, float m1i,
    float m2r, float m2i, float m3r, float m3i) {
  v2f n0r = vfma(sp(-m1i), x1i, vfma(sp(m1r), x1r, vfma(sp(-m0i), x0i, vmul2(sp(m0r), x0r))));
  v2f n0i = vfma(sp( m1i), x1r, vfma(sp(m1r), x1i, vfma(sp( m0i), x0r, vmul2(sp(m0r), x0i))));
  v2f n1r = vfma(sp(-m3i), x1i, vfma(sp(m3r), x1r, vfma(sp(-m2i), x0i, vmul2(sp(m2r), x0r))));
  v2f n1i = vfma(sp( m3i), x1r, vfma(sp(m3r), x1i, vfma(sp( m2i), x0r, vmul2(sp(m2r), x0i))));
  x0r = n0r; x0i = n0i; x1r = n1r; x1i = n1i;
}

// F23: fused (F3*F2) 4x4 on wires 2,3 (lane masks 2,1); ctrl (wire1) bit3.
__device__ __forceinline__ void f23N(v2f Sr[8], v2f Si[8],
    const float* tab, int lane) {
  const int idx = ((lane >> 3) & 1) * 4 + (lane & 3);
  const float* rp = tab + idx * 8;
  const float c0r = rp[0], c0i = rp[1], c1r = rp[2], c1i = rp[3];
  const float c2r = rp[4], c2i = rp[5], c3r = rp[6], c3i = rp[7];
#pragma unroll
  for (int r = 0; r < 8; ++r) {
    v2f p1R = bfly2<1>(Sr[r]), p1I = bfly2<1>(Si[r]);
    v2f p2R = bfly2<2>(Sr[r]), p2I = bfly2<2>(Si[r]);
    v2f p3R = bfly2<3>(Sr[r]), p3I = bfly2<3>(Si[r]);
    v2f nR = vmul2(sp(c0r), Sr[r]);
    nR = vfma(sp(-c0i), Si[r], nR);
    nR = vfma(sp( c1r), p1R, nR);  nR = vfma(sp(-c1i), p1I, nR);
    nR = vfma(sp( c2r), p2R, nR);  nR = vfma(sp(-c2i), p2I, nR);
    nR = vfma(sp( c3r), p3R, nR);  nR = vfma(sp(-c3i), p3I, nR);
    v2f nI = vmul2(sp(c0i), Sr[r]);
    nI = vfma(sp(c0r), Si[r], nI);
    nI = vfma(sp(c1i), p1R, nI);   nI = vfma(sp(c1r), p1I, nI);
    nI = vfma(sp(c2i), p2R, nI);   nI = vfma(sp(c2r), p2I, nI);
    nI = vfma(sp(c3i), p3R, nI);   nI = vfma(sp(c3r), p3I, nI);
    Sr[r] = nR; Si[r] = nI;
  }
}

// F5: u3(w5)+cu3(4->5): ctrl lane mask4 (select), target r bit2.
__device__ __forceinline__ void f5N(v2f Sr[8], v2f Si[8], const float* g, int lane) {
  const bool ct = (lane & 4) != 0;
  float m[8];
#pragma unroll
  for (int jj = 0; jj < 8; ++jj) m[jj] = ct ? g[8 + jj] : g[jj];
#pragma unroll
  for (int r = 0; r < 4; ++r)
    mixP(Sr[r], Si[r], Sr[r + 4], Si[r + 4],
         m[0], m[1], m[2], m[3], m[4], m[5], m[6], m[7]);
}

// F67: fused (F7*F6) 4x4 per reg-quad (r bits 1,0); matrix by r bit2 (w5).
__device__ __forceinline__ void f67N(v2f Sr[8], v2f Si[8], const float* T) {
#pragma unroll
  for (int qd = 0; qd < 2; ++qd) {
    const int B = qd * 4;
    const float* M = T + qd * 32;
    v2f ar0 = Sr[B+0], ai0 = Si[B+0], ar1 = Sr[B+1], ai1 = Si[B+1];
    v2f ar2 = Sr[B+2], ai2 = Si[B+2], ar3 = Sr[B+3], ai3 = Si[B+3];
#pragma unroll
    for (int rp = 0; rp < 4; ++rp) {
      const float* Mr = M + rp * 8;
      v2f nR = vmul2(sp(Mr[0]), ar0);
      nR = vfma(sp(-Mr[1]), ai0, nR);
      nR = vfma(sp( Mr[2]), ar1, nR);
      nR = vfma(sp(-Mr[3]), ai1, nR);
      nR = vfma(sp( Mr[4]), ar2, nR);
      nR = vfma(sp(-Mr[5]), ai2, nR);
      nR = vfma(sp( Mr[6]), ar3, nR);
      nR = vfma(sp(-Mr[7]), ai3, nR);
      v2f nI = vmul2(sp(Mr[1]), ar0);
      nI = vfma(sp(Mr[0]), ai0, nI);
      nI = vfma(sp(Mr[3]), ar1, nI);
      nI = vfma(sp(Mr[2]), ai1, nI);
      nI = vfma(sp(Mr[5]), ar2, nI);
      nI = vfma(sp(Mr[4]), ai2, nI);
      nI = vfma(sp(Mr[7]), ar3, nI);
      nI = vfma(sp(Mr[6]), ai3, nI);
      Sr[B + rp] = nR; Si[B + rp] = nI;
    }
  }
}

// F8': fused cu3(7->0)+next u3(w0): ctrl r bit0, target lane mask 16.
__device__ __forceinline__ void f8pN(v2f Sr[8], v2f Si[8],
    const float* g, int lane) {
  const bool hi = (lane & 16) != 0;
  float fr[2], fi[2], gr[2], gi[2];
  fr[0] = hi ? g[6]  : g[0];  fi[0] = hi ? g[7]  : g[1];
  gr[0] = hi ? g[4]  : g[2];  gi[0] = hi ? g[5]  : g[3];
  fr[1] = hi ? g[14] : g[8];  fi[1] = hi ? g[15] : g[9];
  gr[1] = hi ? g[12] : g[10]; gi[1] = hi ? g[13] : g[11];
#pragma unroll
  for (int r = 0; r < 8; ++r) {
    const int m = r & 1;
    v2f pR = bfly2<16>(Sr[r]);
    v2f pI = bfly2<16>(Si[r]);
    v2f nR = vfma(sp(-gi[m]), pI, vfma(sp(gr[m]), pR, vfma(sp(-fi[m]), Si[r], vmul2(sp(fr[m]), Sr[r]))));
    v2f nI = vfma(sp( gi[m]), pR, vfma(sp(gr[m]), pI, vfma(sp( fi[m]), Sr[r], vmul2(sp(fr[m]), Si[r]))));
    Sr[r] = nR; Si[r] = nI;
  }
}
// F8 final standalone cu3(7->0): odd r only, target lane mask 16.
__device__ __forceinline__ void f8N(v2f Sr[8], v2f Si[8],
    const float* g, int lane) {
  const bool hi = (lane & 16) != 0;
  const float fr = hi ? g[6] : g[0], fi = hi ? g[7] : g[1];
  const float gr = hi ? g[4] : g[2], gi = hi ? g[5] : g[3];
  v2f vfr = sp(fr), vfi = sp(fi), vgr = sp(gr), vgi = sp(gi);
  v2f vfiN = sp(-fi), vgiN = sp(-gi);
#pragma unroll
  for (int r = 1; r < 8; r += 2) {
    v2f pR = bfly2<16>(Sr[r]);
    v2f pI = bfly2<16>(Si[r]);
    v2f nR = vfma(vgiN, pI, vfma(vgr, pR, vfma(vfiN, Si[r], vmul2(vfr, Sr[r]))));
    v2f nI = vfma(vgi,  pR, vfma(vgr, pI, vfma(vfi,  Sr[r], vmul2(vfr, Si[r]))));
    Sr[r] = nR; Si[r] = nI;
  }
}

// Off-diagonal pair sum for a lane-cross wire (mask M).
template<int M>
__device__ __forceinline__ void crossO(const v2f Sr[8], const v2f Si[8],
                                       v2f& re, v2f& im) {
  v2f r = sp(0.0f), iP = sp(0.0f), iN = sp(0.0f);
#pragma unroll
  for (int k = 0; k < 8; ++k) {
    v2f pr = bfly2<M>(Sr[k]);
    v2f pi = bfly2<M>(Si[k]);
    r  = vfma(Sr[k], pr, r);
    r  = vfma(Si[k], pi, r);
    iP = vfma(Si[k], pr, iP);
    iN = vfma(Sr[k], pi, iN);
  }
  re = r; im = vsub2(iP, iN);
}

// ---------------------------------------------------------------------------
// Prep helpers.
// ---------------------------------------------------------------------------
__device__ __forceinline__ void mm2(const float* A, const float* B, float* D) {
  D[0] = A[0]*B[0] - A[1]*B[1] + A[2]*B[4] - A[3]*B[5];
  D[1] = A[0]*B[1] + A[1]*B[0] + A[2]*B[5] + A[3]*B[4];
  D[2] = A[0]*B[2] - A[1]*B[3] + A[2]*B[6] - A[3]*B[7];
  D[3] = A[0]*B[3] + A[1]*B[2] + A[2]*B[7] + A[3]*B[6];
  D[4] = A[4]*B[0] - A[5]*B[1] + A[6]*B[4] - A[7]*B[5];
  D[5] = A[4]*B[1] + A[5]*B[0] + A[6]*B[5] + A[7]*B[4];
  D[6] = A[4]*B[2] - A[5]*B[3] + A[6]*B[6] - A[7]*B[7];
  D[7] = A[4]*B[3] + A[5]*B[2] + A[6]*B[7] + A[7]*B[6];
}
__device__ __forceinline__ void u3fill(const float* src, float* o) {
  float th = src[0], ph = src[1], lam = src[2];
  float c = cosf(0.5f * th), s = sinf(0.5f * th);
  float cl = cosf(lam), sl = sinf(lam);
  float cp = cosf(ph), spv = sinf(ph);
  float cpl = cosf(ph + lam), spl = sinf(ph + lam);
  o[0] = c;        o[1] = 0.0f;
  o[2] = -cl * s;  o[3] = -sl * s;
  o[4] = cp * s;   o[5] = spv * s;
  o[6] = cpl * c;  o[7] = spl * c;
}

// ---------------------------------------------------------------------------
// Fused kernel: conv + qsim + direct-Pauli measurement + FC. 4 px/wave.
// ---------------------------------------------------------------------------
__global__ __launch_bounds__(256, 4) void qconv_kernel(
    const float* __restrict__ x, const float* __restrict__ cw,
    const float* __restrict__ cb, const float* __restrict__ u3p,
    const float* __restrict__ cu3p, const float* __restrict__ fcw,
    const float* __restrict__ fcb, float* __restrict__ out) {
  __shared__ float Us[40][8];
  __shared__ float Cs[40][8];
  __shared__ float Gs[640];
  __shared__ float FCWs[768];   // transposed: [u=0..23][ch=0..31]
  __shared__ float F23t[320];
  __shared__ float F67t[320];

  // ---- in-block prep ----
  {
    const int t = threadIdx.x;
    if (t < 40) u3fill(u3p + t * 3, Us[t]);
    if (t >= 64 && t < 104) u3fill(cu3p + (t - 64) * 3, Cs[t - 64]);
    for (int i = t; i < 768; i += 256) {
      int u = i >> 5, ch = i & 31;
      // lane wires 0..4 double-count pairs in crossO; reg wires 5..7 get x2.
      float sc = (u >= 8 && (u & 7) >= 5) ? 2.0f : 1.0f;
      FCWs[i] = fcw[ch * 24 + u] * sc;
    }
    __syncthreads();
    if (t == 0) {
#pragma unroll
      for (int j = 0; j < 8; ++j) Gs[j] = Us[0][j];
    } else if (t < 36) {
      int j = t - 1, b = j / 7, k = j % 7;
      float* dst = Gs + 8 + b * 112 + k * 16;
      const float* U = Us[b * 8 + k + 1];
      const float* C = Cs[b * 8 + k];
#pragma unroll
      for (int u = 0; u < 8; ++u) dst[u] = U[u];
      mm2(C, U, dst + 8);
    } else if (t < 40) {
      int b = t - 36;
      float* dst = Gs + 568 + b * 16;
      const float* U = Us[(b + 1) * 8];
      const float* C = Cs[b * 8 + 7];
#pragma unroll
      for (int u = 0; u < 8; ++u) dst[u] = U[u];
      mm2(U, C, dst + 8);
    } else if (t == 40) {
#pragma unroll
      for (int j = 0; j < 8; ++j) Gs[632 + j] = Cs[39][j];
    }
    __syncthreads();
    if (t < 40) {
      int b = t >> 3, idx = t & 7;
      int ct = idx >> 2, row = idx & 3;
      const float* M2 = Gs + 8 + b * 112 + 16 + ct * 8;
      int w2p = row >> 1, w3p = row & 1;
      const float* M3 = Gs + 8 + b * 112 + 32 + w2p * 8;
      float* dst = F23t + b * 64 + idx * 8;
#pragma unroll
      for (int k = 0; k < 4; ++k) {
        int w2 = w2p ^ (k >> 1), w3 = w3p ^ (k & 1);
        float a_r = M2[(w2p * 2 + w2) * 2], a_i = M2[(w2p * 2 + w2) * 2 + 1];
        float b_r = M3[(w3p * 2 + w3) * 2], b_i = M3[(w3p * 2 + w3) * 2 + 1];
        dst[k * 2]     = a_r * b_r - a_i * b_i;
        dst[k * 2 + 1] = a_r * b_i + a_i * b_r;
      }
    } else if (t >= 64 && t < 104) {
      int u = t - 64;
      int b = u >> 3, idx = u & 7;
      int ct = idx >> 2, rp = idx & 3;
      const float* M6 = Gs + 8 + b * 112 + 80 + ct * 8;
      int b1p = rp >> 1, b0p = rp & 1;
      const float* M7 = Gs + 8 + b * 112 + 96 + b1p * 8;
      float* dst = F67t + b * 64 + ct * 32 + rp * 8;
#pragma unroll
      for (int c = 0; c < 4; ++c) {
        int b1 = c >> 1, b0 = c & 1;
        float a_r = M6[(b1p * 2 + b1) * 2], a_i = M6[(b1p * 2 + b1) * 2 + 1];
        float b_r = M7[(b0p * 2 + b0) * 2], b_i = M7[(b0p * 2 + b0) * 2 + 1];
        dst[c * 2]     = a_r * b_r - a_i * b_i;
        dst[c * 2 + 1] = a_r * b_i + a_i * b_r;
      }
    }
    __syncthreads();
  }

  const int lane = threadIdx.x & 63;
  const int wid = __builtin_amdgcn_readfirstlane(
      (int)((blockIdx.x * blockDim.x + threadIdx.x) >> 6));
  const int p0 = wid * 4;
  const int q = lane & 31;

  // ---- conv: lane = (px = lane>>4, ichalf = (lane>>3)&1, oc = lane&7) ----
  float ang;
  {
    const int px = lane >> 4;
    const int oc = lane & 7;
    const int ichalf = (lane >> 3) & 1;
    const int p  = p0 + px;
    const int b  = p >> 12;
    const int hh = (p >> 6) & 63;
    const int wim = p & 63;
    float acc = ichalf ? 0.0f : cb[oc];
    const int ic0 = ichalf * 8;
#pragma unroll 4
    for (int ici = 0; ici < 8; ++ici) {
      const int ic = ic0 + ici;
      const float* wp = cw + (oc * 16 + ic) * 9;
      const float* xp = x + (b * 16 + ic) * 4096;
#pragma unroll
      for (int kh = 0; kh < 3; ++kh) {
        int ih = hh + kh - 1;
        bool rok = (unsigned)ih < 64u;
        int ihc = rok ? ih : 0;
#pragma unroll
        for (int kw = 0; kw < 3; ++kw) {
          int iw = wim + kw - 1;
          bool ok = rok && ((unsigned)iw < 64u);
          int iwc = ((unsigned)iw < 64u) ? iw : 0;
          float xv = xp[ihc * 64 + iwc];
          acc = fmaf(ok ? xv : 0.0f, wp[kh * 3 + kw], acc);
        }
      }
    }
    ang = acc + bfly<8>(acc);   // combine the two ic-halves
  }

  // ---- gather 16 angles, build product state with F0 folded ----
  v2f Sr[8], Si[8];
  {
    const int gb = lane & 32;
    float aA[8], aB[8];
#pragma unroll
    for (int w = 0; w < 8; ++w) {
      aA[w] = bperm(ang, (gb + w) << 2);
      aB[w] = bperm(ang, (gb + 16 + w) << 2);
    }
    float cA[8], sA[8], cB[8], sB[8];
#pragma unroll
    for (int w = 0; w < 8; ++w) {
      __sincosf(0.5f * aA[w], &sA[w], &cA[w]);
      __sincosf(0.5f * aB[w], &sB[w], &cB[w]);
    }
    v2f c0; c0.x = cA[0]; c0.y = cB[0];
    v2f s0; s0.x = sA[0]; s0.y = sB[0];
    v2f c0r = vfma(sp(Gs[2]), s0, vmul2(sp(Gs[0]), c0));
    v2f c0i = vfma(sp(Gs[3]), s0, vmul2(sp(Gs[1]), c0));
    v2f s0r = vfma(sp(Gs[6]), s0, vmul2(sp(Gs[4]), c0));
    v2f s0i = vfma(sp(Gs[7]), s0, vmul2(sp(Gs[5]), c0));
    const bool w0 = (q & 16) != 0;
    v2f selR = w0 ? s0r : c0r;
    v2f selI = w0 ? s0i : c0i;
    // lane wires 1..4: masks 8,2,1,4
    float fA = ((q & 8) ? sA[1] : cA[1]) * ((q & 2) ? sA[2] : cA[2])
             * ((q & 1) ? sA[3] : cA[3]) * ((q & 4) ? sA[4] : cA[4]);
    float fB = ((q & 8) ? sB[1] : cB[1]) * ((q & 2) ? sB[2] : cB[2])
             * ((q & 1) ? sB[3] : cB[3]) * ((q & 4) ? sB[4] : cB[4]);
    v2f f; f.x = fA; f.y = fB;
    selR = vmul2(selR, f);
    selI = vmul2(selI, f);
    v2f uu[4];
    uu[0].x = cA[6]*cA[7]; uu[1].x = cA[6]*sA[7];
    uu[2].x = sA[6]*cA[7]; uu[3].x = sA[6]*sA[7];
    uu[0].y = cB[6]*cB[7]; uu[1].y = cB[6]*sB[7];
    uu[2].y = sB[6]*cB[7]; uu[3].y = sB[6]*sB[7];
    v2f v5[2];
    v5[0].x = cA[5]; v5[0].y = cB[5];
    v5[1].x = sA[5]; v5[1].y = sB[5];
#pragma unroll
    for (int r = 0; r < 8; ++r) {
      v2f base = vmul2(v5[r >> 2], uu[r & 3]);
      Sr[r] = vmul2(selR, base);
      Si[r] = vmul2(selI, base);
    }
  }

  // ---- fused circuit: F0 in init; F1,F23,F4,F5,F67,F8' per block ----
  for (int b = 0; b < 5; ++b) {
    const float* base = Gs + 8 + b * 112;
    crossG<8, 16>(Sr, Si, base + 0, lane);      // F1: tgt w1(m8), ctrl w0(m16)
    f23N(Sr, Si, F23t + b * 64, lane);          // F23: m2,m1; ctrl m8
    crossG<4, 1>(Sr, Si, base + 48, lane);      // F4: tgt w4(m4), ctrl w3(m1)
    f5N(Sr, Si, base + 64, lane);               // F5: tgt r bit2, ctrl m4
    f67N(Sr, Si, F67t + b * 64);                // F67: reg 4x4
    if (b < 4) f8pN(Sr, Si, Gs + 568 + b * 16, lane); // F8': tgt m16, ctrl r0
  }
  f8N(Sr, Si, Gs + 632, lane);

  // ---- per-lane measurement partials ----
  float sg[5];
  sg[0] = (q & 16) ? -1.0f : 1.0f;
  sg[1] = (q & 8)  ? -1.0f : 1.0f;
  sg[2] = (q & 2)  ? -1.0f : 1.0f;
  sg[3] = (q & 1)  ? -1.0f : 1.0f;
  sg[4] = (q & 4)  ? -1.0f : 1.0f;

  v2f PT[24];
  {
    v2f re, im;
    crossO<16>(Sr, Si, re, im); PT[8]  = re; PT[16] = vmul2(sp(sg[0]), im);
    crossO<8>(Sr, Si, re, im);  PT[9]  = re; PT[17] = vmul2(sp(sg[1]), im);
    crossO<2>(Sr, Si, re, im);  PT[10] = re; PT[18] = vmul2(sp(sg[2]), im);
    crossO<1>(Sr, Si, re, im);  PT[11] = re; PT[19] = vmul2(sp(sg[3]), im);
    crossO<4>(Sr, Si, re, im);  PT[12] = re; PT[20] = vmul2(sp(sg[4]), im);

    // reg-wire off-diagonal pairs (single orientation; x2 folded into FCWs)
    v2f rA, iP, iN;
    rA = sp(0.0f); iP = sp(0.0f); iN = sp(0.0f);
#pragma unroll
    for (int r = 0; r < 4; ++r) {          // w5: (r, r+4)
      rA = vfma(Sr[r], Sr[r+4], rA); rA = vfma(Si[r], Si[r+4], rA);
      iP = vfma(Si[r], Sr[r+4], iP); iN = vfma(Sr[r], Si[r+4], iN);
    }
    PT[13] = rA; PT[21] = vsub2(iP, iN);
    rA = sp(0.0f); iP = sp(0.0f); iN = sp(0.0f);
#pragma unroll
    for (int t = 0; t < 4; ++t) {          // w6: (lo, lo+2), lo in {0,1,4,5}
      const int lo = (t & 1) + (t >> 1) * 4;
      rA = vfma(Sr[lo], Sr[lo+2], rA); rA = vfma(Si[lo], Si[lo+2], rA);
      iP = vfma(Si[lo], Sr[lo+2], iP); iN = vfma(Sr[lo], Si[lo+2], iN);
    }
    PT[14] = rA; PT[22] = vsub2(iP, iN);
    rA = sp(0.0f); iP = sp(0.0f); iN = sp(0.0f);
#pragma unroll
    for (int t = 0; t < 4; ++t) {          // w7: (2t, 2t+1)
      const int lo = 2 * t;
      rA = vfma(Sr[lo], Sr[lo+1], rA); rA = vfma(Si[lo], Si[lo+1], rA);
      iP = vfma(Si[lo], Sr[lo+1], iP); iN = vfma(Sr[lo], Si[lo+1], iN);
    }
    PT[15] = rA; PT[23] = vsub2(iP, iN);

    // Z: probabilities
    v2f P[8];
#pragma unroll
    for (int r = 0; r < 8; ++r) P[r] = vfma(Si[r], Si[r], vmul2(Sr[r], Sr[r]));
    v2f t01[4];
#pragma unroll
    for (int k = 0; k < 4; ++k) t01[k] = vadd2(P[2*k], P[2*k+1]);
    v2f q0 = vadd2(t01[0], t01[1]), q1 = vadd2(t01[2], t01[3]);
    v2f p  = vadd2(q0, q1);
    PT[5] = vsub2(q0, q1);                                    // w5 (r bit2)
    PT[6] = vadd2(vsub2(t01[0], t01[1]), vsub2(t01[2], t01[3])); // w6
    PT[7] = vadd2(vadd2(vsub2(P[0], P[1]), vsub2(P[2], P[3])),
                  vadd2(vsub2(P[4], P[5]), vsub2(P[6], P[7]))); // w7
    PT[0] = vmul2(sp(sg[0]), p);
    PT[1] = vmul2(sp(sg[1]), p);
    PT[2] = vmul2(sp(sg[2]), p);
    PT[3] = vmul2(sp(sg[3]), p);
    PT[4] = vmul2(sp(sg[4]), p);
  }

  // ---- group-reduce partials (32 lanes, both pixels), then per-channel FC
  const int j = q & 15;
  const bool isB = (q & 16) != 0;
  float mm[24];
#pragma unroll
  for (int t = 0; t < 24; ++t) {
    // own component + partner's (opposite) component via one xor16 swizzle
    float own = isB ? PT[t].y : PT[t].x;
    float oth = isB ? PT[t].x : PT[t].y;
    float s = own + bfly<16>(oth);
    s += bfly<1>(s);
    s += bfly<2>(s);
    s += bfly<4>(s);
    s += bfly<8>(s);                      // completes the 16-lane half sum
    mm[t] = s;
  }

  const int g = lane >> 5;
  const int p = p0 + 2 * g + (isB ? 1 : 0);
  const int ob = (p >> 12) * 131072 + (p & 4095);
#pragma unroll
  for (int k = 0; k < 2; ++k) {
    const int ch = 2 * j + k;
    float acc = fcb[ch];
#pragma unroll
    for (int u = 0; u < 24; ++u) acc = fmaf(mm[u], FCWs[u * 32 + ch], acc);
    out[ob + ch * 4096] = acc;
  }
}

extern "C" void kernel_launch(void* const* d_in, const int* in_sizes, int n_in,
                              void* d_out, int out_size, void* d_ws, size_t ws_size,
                              hipStream_t stream) {
  const float* x      = (const float*)d_in[0];
  const float* conv_w = (const float*)d_in[1];
  const float* conv_b = (const float*)d_in[2];
  const float* u3p    = (const float*)d_in[3];
  const float* cu3p   = (const float*)d_in[4];
  const float* fcw    = (const float*)d_in[5];
  const float* fcb    = (const float*)d_in[6];
  float* out = (float*)d_out;

  qconv_kernel<<<1024, 256, 0, stream>>>(x, conv_w, conv_b, u3p, cu3p,
                                         fcw, fcb, out);
}